// Round 2
// baseline (9687.995 us; speedup 1.0000x reference)
//
#include <hip/hip_runtime.h>
#include <hip/hip_bf16.h>
#include <hip/hip_fp16.h>
#include <stdint.h>

#define NN 50000
#define EE 800000
#define DD 128
#define LL 4

typedef __attribute__((ext_vector_type(8))) short short8;
typedef __attribute__((ext_vector_type(4))) float f32x4;

__device__ __forceinline__ unsigned short f2bf(float x){
  unsigned u = __float_as_uint(x);
  u = (u + 0x7FFFu + ((u >> 16) & 1u)) >> 16;   // RNE
  return (unsigned short)u;
}
__device__ __forceinline__ unsigned encf(float f){   // order-preserving float->uint
  int b = __float_as_int(f);
  return (b >= 0) ? ((unsigned)b | 0x80000000u) : ~((unsigned)b);
}
__device__ __forceinline__ float decf(unsigned u){
  return (u & 0x80000000u) ? __int_as_float((int)(u & 0x7FFFFFFFu))
                           : __int_as_float((int)(~u));
}

// 4 f32 <-> 4 f16 (8B) vector pack/unpack
__device__ __forceinline__ void storeh4(__half* p, float4 v){
  __half2 a = __floats2half2_rn(v.x, v.y);
  __half2 b = __floats2half2_rn(v.z, v.w);
  uint2 u; u.x = *(unsigned*)&a; u.y = *(unsigned*)&b;
  *(uint2*)p = u;
}
__device__ __forceinline__ float4 loadh4(const __half* p){
  uint2 u = *(const uint2*)p;
  __half2 a = *(__half2*)&u.x, b = *(__half2*)&u.y;
  float2 fa = __half22float2(a), fb = __half22float2(b);
  return make_float4(fa.x, fa.y, fb.x, fb.y);
}

// acc[nt] += Atile(16x128) @ W[:, nt*16..nt*16+15]; W transposed bf16 [n][k], row stride 136
__device__ __forceinline__ void gemm8(
    f32x4 acc[8], const short8 af[4], const unsigned short* __restrict__ wt,
    int m15, int q){
  #pragma unroll
  for (int nt = 0; nt < 8; nt++){
    #pragma unroll
    for (int ks = 0; ks < 4; ks++){
      short8 b = *(const short8*)(wt + (nt*16 + m15)*136 + ks*32 + q*8);
      acc[nt] = __builtin_amdgcn_mfma_f32_16x16x32_bf16(af[ks], b, acc[nt], 0, 0, 0);
    }
  }
}

// Cast+transpose the 16 weight matrices to bf16 WT[mat][n][k], stride 136
__global__ void prep_weights_k(const float* __restrict__ A, const float* __restrict__ B,
                               const float* __restrict__ C, const float* __restrict__ V,
                               unsigned short* __restrict__ WT){
  int mat = blockIdx.x >> 6;          // 16 mats x 64 chunks
  int chunk = blockIdx.x & 63;
  int l = mat >> 2, which = mat & 3;
  const float* W = (which == 0) ? A : (which == 1) ? B : (which == 2) ? C : V;
  W += (size_t)l*DD*DD;
  int idx = chunk*256 + threadIdx.x;  // 0..16383
  int nrow = idx >> 7, kk = idx & 127;
  WT[(size_t)mat*DD*136 + nrow*136 + kk] = f2bf(W[kk*DD + nrow]);
}

// X0 = bf16(h)@W0 (and X1 = bf16(h)@W1 if NM==2) over node rows; f16 outputs.
// N-sized: 16x cheaper than per-edge since h[src]@A == (h@A)[src].
template<int NM>
__global__ __launch_bounds__(256, 3) void node_proj_k(
    const float* __restrict__ h_in,
    const unsigned short* __restrict__ wt0,
    const unsigned short* __restrict__ wt1,
    __half* __restrict__ X0, __half* __restrict__ X1)
{
  __shared__ unsigned short shT[64*136];
  __shared__ float outT[64*132];
  const int t = threadIdx.x;
  const int base = blockIdx.x * 64;

  #pragma unroll
  for (int i = 0; i < 8; i++){                 // stage h rows (contiguous) -> bf16
    int c = i*256 + t; int r = c >> 5, cc = c & 31;
    int row = base + r;
    float4 v = make_float4(0.f, 0.f, 0.f, 0.f);
    if (row < NN) v = *(const float4*)(h_in + (size_t)row*DD + cc*4);
    unsigned lo = (unsigned)f2bf(v.x) | ((unsigned)f2bf(v.y) << 16);
    unsigned hi = (unsigned)f2bf(v.z) | ((unsigned)f2bf(v.w) << 16);
    *(uint2*)(shT + r*136 + cc*4) = make_uint2(lo, hi);
  }
  __syncthreads();

  const int lane = t & 63, wv = t >> 6, m15 = lane & 15, q = lane >> 4;
  const int arow = wv*16 + m15;
  short8 af[4];
  #pragma unroll
  for (int ks = 0; ks < 4; ks++)
    af[ks] = *(const short8*)(shT + arow*136 + ks*32 + q*8);

  #pragma unroll
  for (int w = 0; w < NM; w++){
    const unsigned short* wt = w ? wt1 : wt0;
    __half* X = w ? X1 : X0;
    f32x4 acc[8];
    #pragma unroll
    for (int nt = 0; nt < 8; nt++) acc[nt] = (f32x4){0.f, 0.f, 0.f, 0.f};
    gemm8(acc, af, wt, m15, q);
    if (w) __syncthreads();                    // previous writeout done reading outT
    #pragma unroll
    for (int nt = 0; nt < 8; nt++){
      #pragma unroll
      for (int reg = 0; reg < 4; reg++)
        outT[(wv*16 + q*4 + reg)*132 + nt*16 + m15] = acc[nt][reg];
    }
    __syncthreads();
    #pragma unroll
    for (int i = 0; i < 8; i++){
      int c = i*256 + t; int r = c >> 5, cc = c & 31;
      int row = base + r;
      if (row < NN)
        storeh4(X + (size_t)row*DD + cc*4, *(const float4*)(outT + r*132 + cc*4));
    }
  }
}

// e_hat = XA[src] + XB[dst] + e@C ; logits = lrelu(e_hat).a (+atomicMax m) ;
// x_e = e + e_hat written back (in-place safe) ; BN(e) column sums.
__global__ __launch_bounds__(256, 3) void edge_pre_k(
    const float* __restrict__ e_in,
    const int* __restrict__ src, const int* __restrict__ dst,
    const __half* __restrict__ XA, const __half* __restrict__ XB,
    const unsigned short* __restrict__ wtC,
    const float* __restrict__ attn_l,
    float* __restrict__ xe_out, float* __restrict__ logits,
    unsigned* __restrict__ mmax,
    float* __restrict__ esum, float* __restrict__ esum2)
{
  __shared__ unsigned short shE[64*136];  // e rows bf16 (GEMM A-operand)
  __shared__ float T[64*132];             // XA[src]+XB[dst] gather, then e_hat
  const int t = threadIdx.x;
  const int base = blockIdx.x * 64;

  #pragma unroll
  for (int i = 0; i < 8; i++){            // e rows (contiguous) -> bf16 LDS
    int c = i*256 + t; int r = c >> 5, cc = c & 31;
    const float4 v = *(const float4*)(e_in + (size_t)(base + r)*DD + cc*4);
    unsigned lo = (unsigned)f2bf(v.x) | ((unsigned)f2bf(v.y) << 16);
    unsigned hi = (unsigned)f2bf(v.z) | ((unsigned)f2bf(v.w) << 16);
    *(uint2*)(shE + r*136 + cc*4) = make_uint2(lo, hi);
  }
  #pragma unroll
  for (int i = 0; i < 8; i++){            // gather XA[src]+XB[dst] -> T (fp32)
    int c = i*256 + t; int r = c >> 5, cc = c & 31;
    int g1 = src[base + r], g2 = dst[base + r];
    const float4 a = loadh4(XA + (size_t)g1*DD + cc*4);
    const float4 b = loadh4(XB + (size_t)g2*DD + cc*4);
    float4 s; s.x = a.x+b.x; s.y = a.y+b.y; s.z = a.z+b.z; s.w = a.w+b.w;
    *(float4*)(T + r*132 + cc*4) = s;
  }
  __syncthreads();

  const int lane = t & 63, wv = t >> 6, m15 = lane & 15, q = lane >> 4;
  const int arow = wv*16 + m15;
  f32x4 acc[8];
  #pragma unroll
  for (int nt = 0; nt < 8; nt++){         // accumulator init = gathered XA+XB
    #pragma unroll
    for (int reg = 0; reg < 4; reg++)
      acc[nt][reg] = T[(wv*16 + q*4 + reg)*132 + nt*16 + m15];
  }
  short8 af[4];
  #pragma unroll
  for (int ks = 0; ks < 4; ks++)
    af[ks] = *(const short8*)(shE + arow*136 + ks*32 + q*8);
  gemm8(acc, af, wtC, m15, q);            // acc = e_hat

  // logits = leaky_relu(e_hat) . attn  (rows q*4+reg, cols nt*16+m15)
  float av[8];
  #pragma unroll
  for (int nt = 0; nt < 8; nt++) av[nt] = attn_l[nt*16 + m15];
  float p4[4];
  #pragma unroll
  for (int reg = 0; reg < 4; reg++){
    float s = 0.f;
    #pragma unroll
    for (int nt = 0; nt < 8; nt++){
      float v = acc[nt][reg];
      v = (v > 0.f) ? v : 0.2f*v;
      s += v * av[nt];
    }
    p4[reg] = s;
  }
  #pragma unroll
  for (int d_ = 1; d_ < 16; d_ <<= 1){
    #pragma unroll
    for (int reg = 0; reg < 4; reg++) p4[reg] += __shfl_xor(p4[reg], d_);
  }
  if (m15 == 0){
    #pragma unroll
    for (int reg = 0; reg < 4; reg++){
      int R = base + wv*16 + q*4 + reg;
      logits[R] = p4[reg];
      atomicMax(mmax + dst[R], encf(p4[reg]));
    }
  }

  __syncthreads();                        // all waves done with T's init content
  #pragma unroll
  for (int nt = 0; nt < 8; nt++){         // T = e_hat
    #pragma unroll
    for (int reg = 0; reg < 4; reg++)
      T[(wv*16 + q*4 + reg)*132 + nt*16 + m15] = acc[nt][reg];
  }
  __syncthreads();

  { // fused x_e = e + e_hat writeout + BN(e) column partial sums
    int col = t & 127, half = t >> 7;
    float s = 0.f, s2 = 0.f;
    #pragma unroll 4
    for (int r = half*32; r < half*32 + 32; r++){
      float v = e_in[(size_t)(base + r)*DD + col] + T[r*132 + col];
      s += v; s2 += v*v;
      xe_out[(size_t)(base + r)*DD + col] = v;
    }
    atomicAdd(esum + col, s);
    atomicAdd(esum2 + col, s2);
  }
}

__global__ void edge_w_k(float* lw, const int* __restrict__ dst,
                         const unsigned* __restrict__ mmax, float* __restrict__ denom){
  int i = blockIdx.x*256 + threadIdx.x;
  float l = lw[i];
  int d = dst[i];
  float v = __expf(l - decf(mmax[d]));
  lw[i] = v;                       // logits buffer becomes w buffer
  atomicAdd(denom + d, v);
}

// msg = alpha * XV[src]; scatter-add into Q (pre-loaded with h_in copy)
__global__ __launch_bounds__(256) void edge_msg_k(
    const int* __restrict__ src, const int* __restrict__ dst,
    const __half* __restrict__ XV,
    const float* __restrict__ wbuf, const float* __restrict__ denom,
    float* __restrict__ Q)
{
  __shared__ float alphaL[64];
  __shared__ int srcL[64];
  __shared__ int dstL[64];
  const int t = threadIdx.x;
  const int base = blockIdx.x * 64;
  if (t < 64){
    int e_ = base + t;
    int d = dst[e_];
    float den = denom[d];
    alphaL[t] = wbuf[e_] / ((den > 0.f) ? den : 1.f);
    dstL[t] = d;
    srcL[t] = src[e_];
  }
  __syncthreads();
  const int cc = (t & 31) * 4, rb = t >> 5;
  #pragma unroll
  for (int i = 0; i < 8; i++){
    int r = i*8 + rb;
    float al = alphaL[r];
    const float4 v = loadh4(XV + (size_t)srcL[r]*DD + cc);
    float* p = Q + (size_t)dstL[r]*DD + cc;
    atomicAdd(p + 0, al*v.x);
    atomicAdd(p + 1, al*v.y);
    atomicAdd(p + 2, al*v.z);
    atomicAdd(p + 3, al*v.w);
  }
}

// BN stats over Q (= h_in + agg)
__global__ void h_stats_k(const float* __restrict__ Q,
                          float* __restrict__ hsum, float* __restrict__ hsum2){
  int col = threadIdx.x & 127, half = threadIdx.x >> 7;
  int r0 = blockIdx.x*64 + half*32;
  float s = 0.f, s2 = 0.f;
  for (int r = r0; r < r0 + 32; r++){
    if (r < NN){
      float v = Q[(size_t)r*DD + col];
      s += v; s2 += v*v;
    }
  }
  atomicAdd(hsum + col, s);
  atomicAdd(hsum2 + col, s2);
}

// S layout (floats): [hsum 0][hsum2 128][esum 256][esum2 384][sch 512][shh 640][sce 768][she 896]
__global__ void finalize_k(float* __restrict__ S,
                           const float* __restrict__ gh, const float* __restrict__ bh,
                           const float* __restrict__ ge, const float* __restrict__ be){
  int d = threadIdx.x & 127;
  bool is_e = threadIdx.x >= 128;
  const float* s1 = S + (is_e ? 256 : 0);
  const float* s2 = s1 + 128;
  float cnt = is_e ? (float)EE : (float)NN;
  float mu = s1[d] / cnt;
  float var = s2[d] / cnt - mu*mu;
  float rs = rsqrtf(var + 1e-5f);
  const float* g = is_e ? ge : gh;
  const float* b = is_e ? be : bh;
  float scale = rs * g[d];
  S[(is_e ? 768 : 512) + d] = scale;
  S[(is_e ? 896 : 640) + d] = b[d] - mu*scale;
}

// h_out = relu(BN(Q)) in place
__global__ void h_norm_k(float* __restrict__ Q, const float* __restrict__ S){
  size_t i = ((size_t)blockIdx.x*256 + threadIdx.x)*4;
  int col = (int)(i & 127);
  float4 v = *(const float4*)(Q + i);
  const float* sc = S + 512; const float* sh = S + 640;
  v.x = fmaxf(v.x*sc[col+0] + sh[col+0], 0.f);
  v.y = fmaxf(v.y*sc[col+1] + sh[col+1], 0.f);
  v.z = fmaxf(v.z*sc[col+2] + sh[col+2], 0.f);
  v.w = fmaxf(v.w*sc[col+3] + sh[col+3], 0.f);
  *(float4*)(Q + i) = v;
}

__global__ void e_norm_k(float* __restrict__ xe, const float* __restrict__ S){
  size_t i = ((size_t)blockIdx.x*256 + threadIdx.x)*4;
  int col = (int)(i & 127);
  float4 v = *(float4*)(xe + i);
  const float* sc = S + 768; const float* sh = S + 896;
  v.x = fmaxf(v.x*sc[col+0] + sh[col+0], 0.f);
  v.y = fmaxf(v.y*sc[col+1] + sh[col+1], 0.f);
  v.z = fmaxf(v.z*sc[col+2] + sh[col+2], 0.f);
  v.w = fmaxf(v.w*sc[col+3] + sh[col+3], 0.f);
  *(float4*)(xe + i) = v;
}

extern "C" void kernel_launch(void* const* d_in, const int* in_sizes, int n_in,
                              void* d_out, int out_size, void* d_ws, size_t ws_size,
                              hipStream_t stream){
  const float* h0  = (const float*)d_in[0];
  const float* e0  = (const float*)d_in[1];
  const int*  src  = (const int*)d_in[2];
  const int*  dst  = (const int*)d_in[3];
  const float* A   = (const float*)d_in[4];
  const float* B   = (const float*)d_in[5];
  const float* C   = (const float*)d_in[6];
  const float* V   = (const float*)d_in[7];
  const float* attn= (const float*)d_in[8];
  const float* gh  = (const float*)d_in[9];
  const float* bh  = (const float*)d_in[10];
  const float* ge  = (const float*)d_in[11];
  const float* be  = (const float*)d_in[12];

  // ws layout (55,361,152 B == previously verified footprint):
  // WT | logits | ws_h | XA(f16) XB(f16) [XV aliases XA after edge_pre] | mmax denom S
  char* w = (char*)d_ws;
  unsigned short* WT = (unsigned short*)w;                 // 16*128*136*2 = 557,056
  float* logits = (float*)(w + 557056);                    // E*4 = 3,200,000
  float* ws_h   = (float*)(w + 3757056);                   // N*128*4 = 25,600,000
  __half* XA    = (__half*)(w + 29357056);                 // N*128*2 = 12,800,000
  __half* XB    = (__half*)(w + 42157056);                 // N*128*2 = 12,800,000
  __half* XV    = (__half*)(w + 29357056);                 // aliases XA (dead by then)
  char*  zbase  = w + 54957056;
  unsigned* mmax = (unsigned*)zbase;                       // N*4 = 200,000
  float* denom  = (float*)(zbase + 200000);                // N*4 = 200,000
  float* S      = (float*)(zbase + 400000);                // 1024 floats
  const size_t ZBYTES = 200000 + 200000 + 4096;            // end: 55,361,152

  float* hout_sec = (float*)d_out;                         // final h location
  float* ebuf = (float*)d_out + (size_t)NN*DD;             // e ping buffer == final e location

  prep_weights_k<<<1024, 256, 0, stream>>>(A, B, C, V, WT);

  // h state ping-pong: P = input buffer, Q = h_in-copy + message accumulator -> h_out (in place)
  const float* Pb[4] = { h0,   ws_h,     hout_sec, ws_h };
  float*       Qb[4] = { ws_h, hout_sec, ws_h,     hout_sec };

  for (int l = 0; l < LL; l++){
    hipMemsetAsync(zbase, 0, ZBYTES, stream);
    hipMemcpyAsync(Qb[l], Pb[l], (size_t)NN*DD*4, hipMemcpyDeviceToDevice, stream);
    const unsigned short* wtA = WT + (size_t)(l*4 + 0)*DD*136;
    const unsigned short* wtB = WT + (size_t)(l*4 + 1)*DD*136;
    const unsigned short* wtC = WT + (size_t)(l*4 + 2)*DD*136;
    const unsigned short* wtV = WT + (size_t)(l*4 + 3)*DD*136;
    const float* e_in = (l == 0) ? e0 : ebuf;

    node_proj_k<2><<<(NN + 63)/64, 256, 0, stream>>>(Pb[l], wtA, wtB, XA, XB);
    edge_pre_k<<<EE/64, 256, 0, stream>>>(e_in, src, dst, XA, XB,
        wtC, attn + l*DD, ebuf, logits, mmax, S + 256, S + 384);
    edge_w_k<<<EE/256, 256, 0, stream>>>(logits, dst, mmax, denom);
    node_proj_k<1><<<(NN + 63)/64, 256, 0, stream>>>(Pb[l], wtV, wtV, XV, XV);
    edge_msg_k<<<EE/64, 256, 0, stream>>>(src, dst, XV, logits, denom, Qb[l]);
    h_stats_k<<<(NN + 63)/64, 256, 0, stream>>>(Qb[l], S, S + 128);
    finalize_k<<<1, 256, 0, stream>>>(S, gh + l*DD, bh + l*DD, ge + l*DD, be + l*DD);
    h_norm_k<<<(NN*DD)/1024, 256, 0, stream>>>(Qb[l], S);
    e_norm_k<<<(EE*DD)/1024, 256, 0, stream>>>(ebuf, S);
  }
}

// Round 3
// 4483.054 us; speedup vs baseline: 2.1610x; 2.1610x over previous
//
#include <hip/hip_runtime.h>
#include <hip/hip_bf16.h>
#include <hip/hip_fp16.h>
#include <stdint.h>

#define NN 50000
#define EE 800000
#define DD 128
#define LL 4

typedef __attribute__((ext_vector_type(8))) short short8;
typedef __attribute__((ext_vector_type(4))) float f32x4;

__device__ __forceinline__ unsigned short f2bf(float x){
  unsigned u = __float_as_uint(x);
  u = (u + 0x7FFFu + ((u >> 16) & 1u)) >> 16;   // RNE
  return (unsigned short)u;
}

// 4 f32 <-> 4 f16 (8B) vector pack/unpack
__device__ __forceinline__ void storeh4(__half* p, float4 v){
  __half2 a = __floats2half2_rn(v.x, v.y);
  __half2 b = __floats2half2_rn(v.z, v.w);
  uint2 u; u.x = *(unsigned*)&a; u.y = *(unsigned*)&b;
  *(uint2*)p = u;
}
__device__ __forceinline__ float4 loadh4(const __half* p){
  uint2 u = *(const uint2*)p;
  __half2 a = *(__half2*)&u.x, b = *(__half2*)&u.y;
  float2 fa = __half22float2(a), fb = __half22float2(b);
  return make_float4(fa.x, fa.y, fb.x, fb.y);
}

// acc[nt] += Atile(16x128) @ W[:, nt*16..nt*16+15]; W transposed bf16 [n][k], row stride 136
__device__ __forceinline__ void gemm8(
    f32x4 acc[8], const short8 af[4], const unsigned short* __restrict__ wt,
    int m15, int q){
  #pragma unroll
  for (int nt = 0; nt < 8; nt++){
    #pragma unroll
    for (int ks = 0; ks < 4; ks++){
      short8 b = *(const short8*)(wt + (nt*16 + m15)*136 + ks*32 + q*8);
      acc[nt] = __builtin_amdgcn_mfma_f32_16x16x32_bf16(af[ks], b, acc[nt], 0, 0, 0);
    }
  }
}

// Cast+transpose the 16 weight matrices to bf16 WT[mat][n][k], stride 136
__global__ void prep_weights_k(const float* __restrict__ A, const float* __restrict__ B,
                               const float* __restrict__ C, const float* __restrict__ V,
                               unsigned short* __restrict__ WT){
  int mat = blockIdx.x >> 6;          // 16 mats x 64 chunks
  int chunk = blockIdx.x & 63;
  int l = mat >> 2, which = mat & 3;
  const float* W = (which == 0) ? A : (which == 1) ? B : (which == 2) ? C : V;
  W += (size_t)l*DD*DD;
  int idx = chunk*256 + threadIdx.x;  // 0..16383
  int nrow = idx >> 7, kk = idx & 127;
  WT[(size_t)mat*DD*136 + nrow*136 + kk] = f2bf(W[kk*DD + nrow]);
}

// ---- CSR-by-dst build (once per launch; graph static across layers) ----
__global__ void hist_k(const int* __restrict__ dst, int* __restrict__ cnt){
  int i = blockIdx.x*256 + threadIdx.x;
  if (i < EE) atomicAdd(cnt + dst[i], 1);
}

__global__ void scan_k(const int* __restrict__ cnt, int* __restrict__ rowstart){
  __shared__ int part[1024];
  const int t = threadIdx.x;
  const int start = t*49, end = min(start + 49, NN);
  int s = 0;
  for (int i = start; i < end; i++) s += cnt[i];
  part[t] = s;
  __syncthreads();
  for (int d = 1; d < 1024; d <<= 1){           // Hillis-Steele inclusive
    int v = (t >= d) ? part[t - d] : 0;
    __syncthreads();
    part[t] += v;
    __syncthreads();
  }
  int run = (t > 0) ? part[t - 1] : 0;          // exclusive base for this chunk
  for (int i = start; i < end; i++){ rowstart[i] = run; run += cnt[i]; }
  if (t == 0) rowstart[NN] = EE;
}

__global__ void fill_k(const int* __restrict__ dst, const int* __restrict__ rowstart,
                       int* __restrict__ cursor, int* __restrict__ eidx){
  int i = blockIdx.x*256 + threadIdx.x;
  if (i < EE){
    int d = dst[i];
    int pos = atomicAdd(cursor + d, 1);
    eidx[rowstart[d] + pos] = i;
  }
}

// XA = bf16(h)@A, XB = bf16(h)@B, XV = bf16(h)@V over node rows; f16 outputs.
// N-sized: 16x cheaper than per-edge since h[src]@A == (h@A)[src]. H staged once.
__global__ __launch_bounds__(256, 3) void node_proj_k(
    const float* __restrict__ h_in,
    const unsigned short* __restrict__ wtA,
    const unsigned short* __restrict__ wtB,
    const unsigned short* __restrict__ wtV,
    __half* __restrict__ XA, __half* __restrict__ XB, __half* __restrict__ XV)
{
  __shared__ unsigned short shT[64*136];
  __shared__ float outT[64*132];
  const int t = threadIdx.x;
  const int base = blockIdx.x * 64;

  #pragma unroll
  for (int i = 0; i < 8; i++){                 // stage h rows (contiguous) -> bf16
    int c = i*256 + t; int r = c >> 5, cc = c & 31;
    int row = base + r;
    float4 v = make_float4(0.f, 0.f, 0.f, 0.f);
    if (row < NN) v = *(const float4*)(h_in + (size_t)row*DD + cc*4);
    unsigned lo = (unsigned)f2bf(v.x) | ((unsigned)f2bf(v.y) << 16);
    unsigned hi = (unsigned)f2bf(v.z) | ((unsigned)f2bf(v.w) << 16);
    *(uint2*)(shT + r*136 + cc*4) = make_uint2(lo, hi);
  }
  __syncthreads();

  const int lane = t & 63, wv = t >> 6, m15 = lane & 15, q = lane >> 4;
  const int arow = wv*16 + m15;
  short8 af[4];
  #pragma unroll
  for (int ks = 0; ks < 4; ks++)
    af[ks] = *(const short8*)(shT + arow*136 + ks*32 + q*8);

  const unsigned short* wts[3] = { wtA, wtB, wtV };
  __half* Xs[3] = { XA, XB, XV };
  #pragma unroll
  for (int w = 0; w < 3; w++){
    f32x4 acc[8];
    #pragma unroll
    for (int nt = 0; nt < 8; nt++) acc[nt] = (f32x4){0.f, 0.f, 0.f, 0.f};
    gemm8(acc, af, wts[w], m15, q);
    if (w) __syncthreads();                    // previous writeout done reading outT
    #pragma unroll
    for (int nt = 0; nt < 8; nt++){
      #pragma unroll
      for (int reg = 0; reg < 4; reg++)
        outT[(wv*16 + q*4 + reg)*132 + nt*16 + m15] = acc[nt][reg];
    }
    __syncthreads();
    #pragma unroll
    for (int i = 0; i < 8; i++){
      int c = i*256 + t; int r = c >> 5, cc = c & 31;
      int row = base + r;
      if (row < NN)
        storeh4(Xs[w] + (size_t)row*DD + cc*4, *(const float4*)(outT + r*132 + cc*4));
    }
  }
}

// e_hat = XA[src] + XB[dst] + e@C ; logits = lrelu(e_hat).a ;
// x_e = e + e_hat written back (in-place safe) ; BN(e) column sums. No atomicMax.
__global__ __launch_bounds__(256, 3) void edge_pre_k(
    const float* __restrict__ e_in,
    const int* __restrict__ src, const int* __restrict__ dst,
    const __half* __restrict__ XA, const __half* __restrict__ XB,
    const unsigned short* __restrict__ wtC,
    const float* __restrict__ attn_l,
    float* __restrict__ xe_out, float* __restrict__ logits,
    float* __restrict__ esum, float* __restrict__ esum2)
{
  __shared__ unsigned short shE[64*136];  // e rows bf16 (GEMM A-operand)
  __shared__ float T[64*132];             // XA[src]+XB[dst] gather, then e_hat
  const int t = threadIdx.x;
  const int base = blockIdx.x * 64;

  #pragma unroll
  for (int i = 0; i < 8; i++){            // e rows (contiguous) -> bf16 LDS
    int c = i*256 + t; int r = c >> 5, cc = c & 31;
    const float4 v = *(const float4*)(e_in + (size_t)(base + r)*DD + cc*4);
    unsigned lo = (unsigned)f2bf(v.x) | ((unsigned)f2bf(v.y) << 16);
    unsigned hi = (unsigned)f2bf(v.z) | ((unsigned)f2bf(v.w) << 16);
    *(uint2*)(shE + r*136 + cc*4) = make_uint2(lo, hi);
  }
  #pragma unroll
  for (int i = 0; i < 8; i++){            // gather XA[src]+XB[dst] -> T (fp32)
    int c = i*256 + t; int r = c >> 5, cc = c & 31;
    int g1 = src[base + r], g2 = dst[base + r];
    const float4 a = loadh4(XA + (size_t)g1*DD + cc*4);
    const float4 b = loadh4(XB + (size_t)g2*DD + cc*4);
    float4 s; s.x = a.x+b.x; s.y = a.y+b.y; s.z = a.z+b.z; s.w = a.w+b.w;
    *(float4*)(T + r*132 + cc*4) = s;
  }
  __syncthreads();

  const int lane = t & 63, wv = t >> 6, m15 = lane & 15, q = lane >> 4;
  const int arow = wv*16 + m15;
  f32x4 acc[8];
  #pragma unroll
  for (int nt = 0; nt < 8; nt++){         // accumulator init = gathered XA+XB
    #pragma unroll
    for (int reg = 0; reg < 4; reg++)
      acc[nt][reg] = T[(wv*16 + q*4 + reg)*132 + nt*16 + m15];
  }
  short8 af[4];
  #pragma unroll
  for (int ks = 0; ks < 4; ks++)
    af[ks] = *(const short8*)(shE + arow*136 + ks*32 + q*8);
  gemm8(acc, af, wtC, m15, q);            // acc = e_hat

  // logits = leaky_relu(e_hat) . attn  (rows q*4+reg, cols nt*16+m15)
  float av[8];
  #pragma unroll
  for (int nt = 0; nt < 8; nt++) av[nt] = attn_l[nt*16 + m15];
  float p4[4];
  #pragma unroll
  for (int reg = 0; reg < 4; reg++){
    float s = 0.f;
    #pragma unroll
    for (int nt = 0; nt < 8; nt++){
      float v = acc[nt][reg];
      v = (v > 0.f) ? v : 0.2f*v;
      s += v * av[nt];
    }
    p4[reg] = s;
  }
  #pragma unroll
  for (int d_ = 1; d_ < 16; d_ <<= 1){
    #pragma unroll
    for (int reg = 0; reg < 4; reg++) p4[reg] += __shfl_xor(p4[reg], d_);
  }
  if (m15 == 0){
    #pragma unroll
    for (int reg = 0; reg < 4; reg++)
      logits[base + wv*16 + q*4 + reg] = p4[reg];
  }

  __syncthreads();                        // all waves done with T's init content
  #pragma unroll
  for (int nt = 0; nt < 8; nt++){         // T = e_hat
    #pragma unroll
    for (int reg = 0; reg < 4; reg++)
      T[(wv*16 + q*4 + reg)*132 + nt*16 + m15] = acc[nt][reg];
  }
  __syncthreads();

  { // fused x_e = e + e_hat writeout + BN(e) column partial sums
    int col = t & 127, half = t >> 7;
    float s = 0.f, s2 = 0.f;
    #pragma unroll 4
    for (int r = half*32; r < half*32 + 32; r++){
      float v = e_in[(size_t)(base + r)*DD + col] + T[r*132 + col];
      s += v; s2 += v*v;
      xe_out[(size_t)(base + r)*DD + col] = v;
    }
    atomicAdd(esum + col, s);
    atomicAdd(esum2 + col, s2);
  }
}

// One wave per dst node: local softmax over its in-edges (CSR) + weighted XV
// accumulation. Zero atomics; H updated in place (row n read/written only here).
__global__ __launch_bounds__(256) void node_agg_k(
    const int* __restrict__ rowstart, const int* __restrict__ eidx,
    const int* __restrict__ src, const float* __restrict__ logits,
    const __half* __restrict__ XV, float* __restrict__ H)
{
  int node = blockIdx.x*4 + (threadIdx.x >> 6);
  if (node >= NN) return;
  const int lane = threadIdx.x & 63;
  const int s = rowstart[node], e_end = rowstart[node + 1];
  const int deg = e_end - s;

  // pass 1: wave max + denom over in-edges (lane-strided), cache first chunk in regs
  float m = -3.4e38f;
  float myL = -3.4e38f; int mySrc = 0;
  for (int p = s + lane; p < e_end; p += 64){
    int e = eidx[p];
    float l = logits[e];
    if (p - s < 64){ myL = l; mySrc = src[e]; }
    m = fmaxf(m, l);
  }
  #pragma unroll
  for (int d = 1; d < 64; d <<= 1) m = fmaxf(m, __shfl_xor(m, d));
  float den = 0.f;
  for (int p = s + lane; p < e_end; p += 64)
    den += __expf(logits[eidx[p]] - m);
  #pragma unroll
  for (int d = 1; d < 64; d <<= 1) den += __shfl_xor(den, d);
  const float dinv = (deg > 0) ? 1.f/den : 0.f;   // den >= 1 when deg > 0

  // pass 2: accumulate; lane owns cols 2*lane, 2*lane+1; edges broadcast via shfl
  float a0 = 0.f, a1 = 0.f;
  for (int cb = s; cb < e_end; cb += 64){
    int n = min(64, e_end - cb);
    float cl; int cs_;
    if (cb == s){ cl = myL; cs_ = mySrc; }
    else {
      cl = 0.f; cs_ = 0;
      if (lane < n){ int e = eidx[cb + lane]; cl = logits[e]; cs_ = src[e]; }
    }
    for (int j = 0; j < n; j++){
      float w = __expf(__shfl(cl, j) - m) * dinv;
      int sj = __shfl(cs_, j);
      float2 f = __half22float2(*(const __half2*)(XV + (size_t)sj*DD + lane*2));
      a0 += w*f.x; a1 += w*f.y;
    }
  }
  size_t o = (size_t)node*DD + lane*2;
  float2 hv = *(const float2*)(H + o);
  *(float2*)(H + o) = make_float2(hv.x + a0, hv.y + a1);
}

// BN stats over H (= h_in + agg, already in place)
__global__ void h_stats_k(const float* __restrict__ H,
                          float* __restrict__ hsum, float* __restrict__ hsum2){
  int col = threadIdx.x & 127, half = threadIdx.x >> 7;
  int r0 = blockIdx.x*64 + half*32;
  float s = 0.f, s2 = 0.f;
  for (int r = r0; r < r0 + 32; r++){
    if (r < NN){
      float v = H[(size_t)r*DD + col];
      s += v; s2 += v*v;
    }
  }
  atomicAdd(hsum + col, s);
  atomicAdd(hsum2 + col, s2);
}

// S layout (floats): [hsum 0][hsum2 128][esum 256][esum2 384][sch 512][shh 640][sce 768][she 896]
__global__ void finalize_k(float* __restrict__ S,
                           const float* __restrict__ gh, const float* __restrict__ bh,
                           const float* __restrict__ ge, const float* __restrict__ be){
  int d = threadIdx.x & 127;
  bool is_e = threadIdx.x >= 128;
  const float* s1 = S + (is_e ? 256 : 0);
  const float* s2 = s1 + 128;
  float cnt = is_e ? (float)EE : (float)NN;
  float mu = s1[d] / cnt;
  float var = s2[d] / cnt - mu*mu;
  float rs = rsqrtf(var + 1e-5f);
  const float* g = is_e ? ge : gh;
  const float* b = is_e ? be : bh;
  float scale = rs * g[d];
  S[(is_e ? 768 : 512) + d] = scale;
  S[(is_e ? 896 : 640) + d] = b[d] - mu*scale;
}

// h = relu(BN(h)) in place
__global__ void h_norm_k(float* __restrict__ H, const float* __restrict__ S){
  size_t i = ((size_t)blockIdx.x*256 + threadIdx.x)*4;
  int col = (int)(i & 127);
  float4 v = *(const float4*)(H + i);
  const float* sc = S + 512; const float* sh = S + 640;
  v.x = fmaxf(v.x*sc[col+0] + sh[col+0], 0.f);
  v.y = fmaxf(v.y*sc[col+1] + sh[col+1], 0.f);
  v.z = fmaxf(v.z*sc[col+2] + sh[col+2], 0.f);
  v.w = fmaxf(v.w*sc[col+3] + sh[col+3], 0.f);
  *(float4*)(H + i) = v;
}

__global__ void e_norm_k(float* __restrict__ xe, const float* __restrict__ S){
  size_t i = ((size_t)blockIdx.x*256 + threadIdx.x)*4;
  int col = (int)(i & 127);
  float4 v = *(float4*)(xe + i);
  const float* sc = S + 768; const float* sh = S + 896;
  v.x = fmaxf(v.x*sc[col+0] + sh[col+0], 0.f);
  v.y = fmaxf(v.y*sc[col+1] + sh[col+1], 0.f);
  v.z = fmaxf(v.z*sc[col+2] + sh[col+2], 0.f);
  v.w = fmaxf(v.w*sc[col+3] + sh[col+3], 0.f);
  *(float4*)(xe + i) = v;
}

extern "C" void kernel_launch(void* const* d_in, const int* in_sizes, int n_in,
                              void* d_out, int out_size, void* d_ws, size_t ws_size,
                              hipStream_t stream){
  const float* h0  = (const float*)d_in[0];
  const float* e0  = (const float*)d_in[1];
  const int*  src  = (const int*)d_in[2];
  const int*  dst  = (const int*)d_in[3];
  const float* A   = (const float*)d_in[4];
  const float* B   = (const float*)d_in[5];
  const float* C   = (const float*)d_in[6];
  const float* V   = (const float*)d_in[7];
  const float* attn= (const float*)d_in[8];
  const float* gh  = (const float*)d_in[9];
  const float* bh  = (const float*)d_in[10];
  const float* ge  = (const float*)d_in[11];
  const float* be  = (const float*)d_in[12];

  // ws layout (45,761,216 B): WT | logits | XA XB XV (f16) | rowstart eidx cursor | S
  char* w = (char*)d_ws;
  unsigned short* WT = (unsigned short*)w;                 // 557,056
  float* logits  = (float*)(w + 557056);                   // E*4 = 3,200,000
  __half* XA     = (__half*)(w + 3757056);                 // N*128*2 = 12,800,000
  __half* XB     = (__half*)(w + 16557056);                // 12,800,000
  __half* XV     = (__half*)(w + 29357056);                // 12,800,000
  int* rowstart  = (int*)(w + 42157056);                   // (N+1)*4 -> 200,064
  int* eidx      = (int*)(w + 42357120);                   // E*4 = 3,200,000
  int* cursor    = (int*)(w + 45557120);                   // N*4 = 200,000
  float* S       = (float*)(w + 45757120);                 // 1024 floats

  float* H    = (float*)d_out;                             // node state, in place
  float* ebuf = (float*)d_out + (size_t)NN*DD;             // e state, in place

  // one-time: weights, h0 copy, CSR-by-dst
  prep_weights_k<<<1024, 256, 0, stream>>>(A, B, C, V, WT);
  hipMemcpyAsync(H, h0, (size_t)NN*DD*4, hipMemcpyDeviceToDevice, stream);
  hipMemsetAsync(cursor, 0, NN*4, stream);
  hist_k<<<EE/256, 256, 0, stream>>>(dst, cursor);
  scan_k<<<1, 1024, 0, stream>>>(cursor, rowstart);
  hipMemsetAsync(cursor, 0, NN*4, stream);
  fill_k<<<EE/256, 256, 0, stream>>>(dst, rowstart, cursor, eidx);

  for (int l = 0; l < LL; l++){
    hipMemsetAsync(S, 0, 4096, stream);
    const unsigned short* wtA = WT + (size_t)(l*4 + 0)*DD*136;
    const unsigned short* wtB = WT + (size_t)(l*4 + 1)*DD*136;
    const unsigned short* wtC = WT + (size_t)(l*4 + 2)*DD*136;
    const unsigned short* wtV = WT + (size_t)(l*4 + 3)*DD*136;
    const float* e_in = (l == 0) ? e0 : ebuf;

    node_proj_k<<<(NN + 63)/64, 256, 0, stream>>>(H, wtA, wtB, wtV, XA, XB, XV);
    edge_pre_k<<<EE/64, 256, 0, stream>>>(e_in, src, dst, XA, XB,
        wtC, attn + l*DD, ebuf, logits, S + 256, S + 384);
    node_agg_k<<<(NN + 3)/4, 256, 0, stream>>>(rowstart, eidx, src, logits, XV, H);
    h_stats_k<<<(NN + 63)/64, 256, 0, stream>>>(H, S, S + 128);
    finalize_k<<<1, 256, 0, stream>>>(S, gh + l*DD, bh + l*DD, ge + l*DD, be + l*DD);
    h_norm_k<<<(NN*DD)/1024, 256, 0, stream>>>(H, S);
    e_norm_k<<<(EE*DD)/1024, 256, 0, stream>>>(ebuf, S);
  }
}

// Round 5
// 2765.926 us; speedup vs baseline: 3.5026x; 1.6208x over previous
//
#include <hip/hip_runtime.h>
#include <hip/hip_bf16.h>
#include <hip/hip_fp16.h>
#include <stdint.h>

#define NN 50000
#define EE 800000
#define DD 128
#define LL 4

typedef __attribute__((ext_vector_type(8))) short short8;
typedef __attribute__((ext_vector_type(4))) float f32x4;

// S float offsets: [hsum 0][hsum2 128][e-banks 256..2303: 8 x (esum128,esum2 128)]
// persistent: [sch 2304][shh 2432][sce 2560][she 2688]  (total 2816 floats)
#define S_EBANK 256
#define S_SCH 2304
#define S_SHH 2432
#define S_SCE 2560
#define S_SHE 2688
#define S_ZERO_BYTES 9216   // floats 0..2303

__device__ __forceinline__ unsigned short f2bf(float x){
  unsigned u = __float_as_uint(x);
  u = (u + 0x7FFFu + ((u >> 16) & 1u)) >> 16;   // RNE
  return (unsigned short)u;
}

__device__ __forceinline__ void storeh4(__half* p, float4 v){
  __half2 a = __floats2half2_rn(v.x, v.y);
  __half2 b = __floats2half2_rn(v.z, v.w);
  uint2 u; u.x = *(unsigned*)&a; u.y = *(unsigned*)&b;
  *(uint2*)p = u;
}
__device__ __forceinline__ float4 loadh4(const __half* p){
  uint2 u = *(const uint2*)p;
  __half2 a = *(__half2*)&u.x, b = *(__half2*)&u.y;
  float2 fa = __half22float2(a), fb = __half22float2(b);
  return make_float4(fa.x, fa.y, fb.x, fb.y);
}

// acc[nt] += Atile(16x128) @ W[:, nt*16..nt*16+15]; W transposed bf16 [n][k], row stride 136
__device__ __forceinline__ void gemm8(
    f32x4 acc[8], const short8 af[4], const unsigned short* __restrict__ wt,
    int m15, int q){
  #pragma unroll
  for (int nt = 0; nt < 8; nt++){
    #pragma unroll
    for (int ks = 0; ks < 4; ks++){
      short8 b = *(const short8*)(wt + (nt*16 + m15)*136 + ks*32 + q*8);
      acc[nt] = __builtin_amdgcn_mfma_f32_16x16x32_bf16(af[ks], b, acc[nt], 0, 0, 0);
    }
  }
}

// Cast+transpose the 16 weight matrices to bf16 WT[mat][n][k], stride 136
__global__ void prep_weights_k(const float* __restrict__ A, const float* __restrict__ B,
                               const float* __restrict__ C, const float* __restrict__ V,
                               unsigned short* __restrict__ WT){
  int mat = blockIdx.x >> 6;          // 16 mats x 64 chunks
  int chunk = blockIdx.x & 63;
  int l = mat >> 2, which = mat & 3;
  const float* W = (which == 0) ? A : (which == 1) ? B : (which == 2) ? C : V;
  W += (size_t)l*DD*DD;
  int idx = chunk*256 + threadIdx.x;  // 0..16383
  int nrow = idx >> 7, kk = idx & 127;
  WT[(size_t)mat*DD*136 + nrow*136 + kk] = f2bf(W[kk*DD + nrow]);
}

// ---- CSR-by-dst build (once per launch; graph static across layers) ----
__global__ void hist_k(const int* __restrict__ dst, int* __restrict__ cnt){
  int i = blockIdx.x*256 + threadIdx.x;
  if (i < EE) atomicAdd(cnt + dst[i], 1);
}

__global__ void scan_k(const int* __restrict__ cnt, int* __restrict__ rowstart){
  __shared__ int part[1024];
  const int t = threadIdx.x;
  const int start = t*49, end = min(start + 49, NN);
  int s = 0;
  for (int i = start; i < end; i++) s += cnt[i];
  part[t] = s;
  __syncthreads();
  for (int d = 1; d < 1024; d <<= 1){           // Hillis-Steele inclusive
    int v = (t >= d) ? part[t - d] : 0;
    __syncthreads();
    part[t] += v;
    __syncthreads();
  }
  int run = (t > 0) ? part[t - 1] : 0;          // exclusive base for this chunk
  for (int i = start; i < end; i++){ rowstart[i] = run; run += cnt[i]; }
  if (t == 0) rowstart[NN] = EE;
}

__global__ void fill_k(const int* __restrict__ dst, const int* __restrict__ rowstart,
                       int* __restrict__ cursor, int* __restrict__ eidx){
  int i = blockIdx.x*256 + threadIdx.x;
  if (i < EE){
    int d = dst[i];
    int pos = atomicAdd(cursor + d, 1);
    eidx[rowstart[d] + pos] = i;
  }
}

// XA/XB/XV = bf16(h)@{A,B,V} over node rows; f16 outputs. N-sized (16x cheaper than
// per-edge since h[src]@A == (h@A)[src]). H staged once.
__global__ __launch_bounds__(256, 3) void node_proj_k(
    const float* __restrict__ h_in,
    const unsigned short* __restrict__ wtA,
    const unsigned short* __restrict__ wtB,
    const unsigned short* __restrict__ wtV,
    __half* __restrict__ XA, __half* __restrict__ XB, __half* __restrict__ XV)
{
  __shared__ unsigned short shT[64*136];
  __shared__ float outT[64*132];
  const int t = threadIdx.x;
  const int base = blockIdx.x * 64;

  #pragma unroll
  for (int i = 0; i < 8; i++){                 // stage h rows (contiguous) -> bf16
    int c = i*256 + t; int r = c >> 5, cc = c & 31;
    int row = base + r;
    float4 v = make_float4(0.f, 0.f, 0.f, 0.f);
    if (row < NN) v = *(const float4*)(h_in + (size_t)row*DD + cc*4);
    unsigned lo = (unsigned)f2bf(v.x) | ((unsigned)f2bf(v.y) << 16);
    unsigned hi = (unsigned)f2bf(v.z) | ((unsigned)f2bf(v.w) << 16);
    *(uint2*)(shT + r*136 + cc*4) = make_uint2(lo, hi);
  }
  __syncthreads();

  const int lane = t & 63, wv = t >> 6, m15 = lane & 15, q = lane >> 4;
  const int arow = wv*16 + m15;
  short8 af[4];
  #pragma unroll
  for (int ks = 0; ks < 4; ks++)
    af[ks] = *(const short8*)(shT + arow*136 + ks*32 + q*8);

  const unsigned short* wts[3] = { wtA, wtB, wtV };
  __half* Xs[3] = { XA, XB, XV };
  #pragma unroll
  for (int w = 0; w < 3; w++){
    f32x4 acc[8];
    #pragma unroll
    for (int nt = 0; nt < 8; nt++) acc[nt] = (f32x4){0.f, 0.f, 0.f, 0.f};
    gemm8(acc, af, wts[w], m15, q);
    if (w) __syncthreads();                    // previous writeout done reading outT
    #pragma unroll
    for (int nt = 0; nt < 8; nt++){
      #pragma unroll
      for (int reg = 0; reg < 4; reg++)
        outT[(wv*16 + q*4 + reg)*132 + nt*16 + m15] = acc[nt][reg];
    }
    __syncthreads();
    #pragma unroll
    for (int i = 0; i < 8; i++){
      int c = i*256 + t; int r = c >> 5, cc = c & 31;
      int row = base + r;
      if (row < NN)
        storeh4(Xs[w] + (size_t)row*DD + cc*4, *(const float4*)(outT + r*132 + cc*4));
    }
  }
}

// e_n = DONORM ? relu(e_raw*sc+sh) : e_raw   (fused BN+ReLU of previous layer)
// e_hat = XA[src] + XB[dst] + e_n@C ; logits = lrelu(e_hat).a ;
// x_e = e_n + e_hat written to xe_out (pre-norm, normed on next layer's read);
// BN(x_e) column sums into 8 spread banks. LDS: T only (~34.8K) -> 4 blocks/CU.
// NOTE: e_raw / xe_out intentionally NOT __restrict__ (they alias for l>=1).
template<int DONORM>
__global__ __launch_bounds__(256, 4) void edge_pre_k(
    const float* e_raw,
    const int* __restrict__ src, const int* __restrict__ dst,
    const __half* __restrict__ XA, const __half* __restrict__ XB,
    const unsigned short* __restrict__ wtC,
    const float* __restrict__ attn_l,
    float* xe_out, float* __restrict__ logits,
    float* __restrict__ S)
{
  __shared__ float T[64*132];             // XA[src]+XB[dst] gather, then e_hat
  __shared__ float shSC[128], shSH[128];
  const int t = threadIdx.x;
  const int base = blockIdx.x * 64;

  if (DONORM){
    if (t < 128) shSC[t] = S[S_SCE + t];
    else         shSH[t - 128] = S[S_SHE + (t - 128)];
  }
  #pragma unroll
  for (int i = 0; i < 8; i++){            // gather XA[src]+XB[dst] -> T (fp32)
    int c = i*256 + t; int r = c >> 5, cc = c & 31;
    int g1 = src[base + r], g2 = dst[base + r];
    const float4 a = loadh4(XA + (size_t)g1*DD + cc*4);
    const float4 b = loadh4(XB + (size_t)g2*DD + cc*4);
    float4 s; s.x = a.x+b.x; s.y = a.y+b.y; s.z = a.z+b.z; s.w = a.w+b.w;
    *(float4*)(T + r*132 + cc*4) = s;
  }
  __syncthreads();

  const int lane = t & 63, wv = t >> 6, m15 = lane & 15, q = lane >> 4;
  const int arow = wv*16 + m15;

  // A-fragments direct from global with fused norm (no LDS stage for e)
  const float* erow = e_raw + (size_t)(base + arow)*DD;
  short8 af[4];
  #pragma unroll
  for (int ks = 0; ks < 4; ks++){
    const int c0 = ks*32 + q*8;
    float4 v0 = *(const float4*)(erow + c0);
    float4 v1 = *(const float4*)(erow + c0 + 4);
    if (DONORM){
      v0.x = fmaxf(fmaf(v0.x, shSC[c0+0], shSH[c0+0]), 0.f);
      v0.y = fmaxf(fmaf(v0.y, shSC[c0+1], shSH[c0+1]), 0.f);
      v0.z = fmaxf(fmaf(v0.z, shSC[c0+2], shSH[c0+2]), 0.f);
      v0.w = fmaxf(fmaf(v0.w, shSC[c0+3], shSH[c0+3]), 0.f);
      v1.x = fmaxf(fmaf(v1.x, shSC[c0+4], shSH[c0+4]), 0.f);
      v1.y = fmaxf(fmaf(v1.y, shSC[c0+5], shSH[c0+5]), 0.f);
      v1.z = fmaxf(fmaf(v1.z, shSC[c0+6], shSH[c0+6]), 0.f);
      v1.w = fmaxf(fmaf(v1.w, shSC[c0+7], shSH[c0+7]), 0.f);
    }
    short8 a;
    a[0]=(short)f2bf(v0.x); a[1]=(short)f2bf(v0.y); a[2]=(short)f2bf(v0.z); a[3]=(short)f2bf(v0.w);
    a[4]=(short)f2bf(v1.x); a[5]=(short)f2bf(v1.y); a[6]=(short)f2bf(v1.z); a[7]=(short)f2bf(v1.w);
    af[ks] = a;
  }

  f32x4 acc[8];
  #pragma unroll
  for (int nt = 0; nt < 8; nt++){         // accumulator init = gathered XA+XB
    #pragma unroll
    for (int reg = 0; reg < 4; reg++)
      acc[nt][reg] = T[(wv*16 + q*4 + reg)*132 + nt*16 + m15];
  }
  gemm8(acc, af, wtC, m15, q);            // acc = e_hat

  // logits = leaky_relu(e_hat) . attn  (rows q*4+reg, cols nt*16+m15)
  float av[8];
  #pragma unroll
  for (int nt = 0; nt < 8; nt++) av[nt] = attn_l[nt*16 + m15];
  float p4[4];
  #pragma unroll
  for (int reg = 0; reg < 4; reg++){
    float s = 0.f;
    #pragma unroll
    for (int nt = 0; nt < 8; nt++){
      float v = acc[nt][reg];
      v = (v > 0.f) ? v : 0.2f*v;
      s += v * av[nt];
    }
    p4[reg] = s;
  }
  #pragma unroll
  for (int d_ = 1; d_ < 16; d_ <<= 1){
    #pragma unroll
    for (int reg = 0; reg < 4; reg++) p4[reg] += __shfl_xor(p4[reg], d_);
  }
  if (m15 == 0){
    #pragma unroll
    for (int reg = 0; reg < 4; reg++)
      logits[base + wv*16 + q*4 + reg] = p4[reg];
  }

  __syncthreads();                        // all waves done with T's init content
  #pragma unroll
  for (int nt = 0; nt < 8; nt++){         // T = e_hat
    #pragma unroll
    for (int reg = 0; reg < 4; reg++)
      T[(wv*16 + q*4 + reg)*132 + nt*16 + m15] = acc[nt][reg];
  }
  __syncthreads();

  { // fused x_e = e_n + e_hat writeout + BN(x_e) column partial sums
    const int col = t & 127, half = t >> 7;
    const float sc = DONORM ? shSC[col] : 1.f;
    const float sh = DONORM ? shSH[col] : 0.f;
    float s = 0.f, s2 = 0.f;
    #pragma unroll 4
    for (int r = half*32; r < half*32 + 32; r++){
      float ev = e_raw[(size_t)(base + r)*DD + col];      // L2 hit (re-read)
      if (DONORM) ev = fmaxf(fmaf(ev, sc, sh), 0.f);
      float v = ev + T[r*132 + col];
      s += v; s2 += v*v;
      xe_out[(size_t)(base + r)*DD + col] = v;
    }
    float* eb = S + S_EBANK + (blockIdx.x & 7)*256;       // 8-way spread banks
    atomicAdd(eb + col, s);
    atomicAdd(eb + 128 + col, s2);
  }
}

// One wave per dst node: local softmax over its in-edges (CSR) + weighted XV
// accumulation. Zero atomics; H updated in place.
__global__ __launch_bounds__(256) void node_agg_k(
    const int* __restrict__ rowstart, const int* __restrict__ eidx,
    const int* __restrict__ src, const float* __restrict__ logits,
    const __half* __restrict__ XV, float* __restrict__ H)
{
  int node = blockIdx.x*4 + (threadIdx.x >> 6);
  if (node >= NN) return;
  const int lane = threadIdx.x & 63;
  const int s = rowstart[node], e_end = rowstart[node + 1];
  const int deg = e_end - s;

  float m = -3.4e38f;
  float myL = -3.4e38f; int mySrc = 0;
  for (int p = s + lane; p < e_end; p += 64){
    int e = eidx[p];
    float l = logits[e];
    if (p - s < 64){ myL = l; mySrc = src[e]; }
    m = fmaxf(m, l);
  }
  #pragma unroll
  for (int d = 1; d < 64; d <<= 1) m = fmaxf(m, __shfl_xor(m, d));
  float den = 0.f;
  for (int p = s + lane; p < e_end; p += 64)
    den += __expf(logits[eidx[p]] - m);
  #pragma unroll
  for (int d = 1; d < 64; d <<= 1) den += __shfl_xor(den, d);
  const float dinv = (deg > 0) ? 1.f/den : 0.f;

  float a0 = 0.f, a1 = 0.f;
  for (int cb = s; cb < e_end; cb += 64){
    int n = min(64, e_end - cb);
    float cl; int cs_;
    if (cb == s){ cl = myL; cs_ = mySrc; }
    else {
      cl = 0.f; cs_ = 0;
      if (lane < n){ int e = eidx[cb + lane]; cl = logits[e]; cs_ = src[e]; }
    }
    for (int j = 0; j < n; j++){
      float w = __expf(__shfl(cl, j) - m) * dinv;
      int sj = __shfl(cs_, j);
      float2 f = __half22float2(*(const __half2*)(XV + (size_t)sj*DD + lane*2));
      a0 += w*f.x; a1 += w*f.y;
    }
  }
  size_t o = (size_t)node*DD + lane*2;
  float2 hv = *(const float2*)(H + o);
  *(float2*)(H + o) = make_float2(hv.x + a0, hv.y + a1);
}

// BN stats over H (= h_in + agg, already in place)
__global__ void h_stats_k(const float* __restrict__ H,
                          float* __restrict__ hsum, float* __restrict__ hsum2){
  int col = threadIdx.x & 127, half = threadIdx.x >> 7;
  int r0 = blockIdx.x*64 + half*32;
  float s = 0.f, s2 = 0.f;
  for (int r = r0; r < r0 + 32; r++){
    if (r < NN){
      float v = H[(size_t)r*DD + col];
      s += v; s2 += v*v;
    }
  }
  atomicAdd(hsum + col, s);
  atomicAdd(hsum2 + col, s2);
}

__global__ void finalize_k(float* __restrict__ S,
                           const float* __restrict__ gh, const float* __restrict__ bh,
                           const float* __restrict__ ge, const float* __restrict__ be){
  int d = threadIdx.x & 127;
  bool is_e = threadIdx.x >= 128;
  float s1v, s2v, cnt;
  if (is_e){
    s1v = 0.f; s2v = 0.f;
    #pragma unroll
    for (int b = 0; b < 8; b++){
      s1v += S[S_EBANK + b*256 + d];
      s2v += S[S_EBANK + b*256 + 128 + d];
    }
    cnt = (float)EE;
  } else {
    s1v = S[d]; s2v = S[128 + d]; cnt = (float)NN;
  }
  float mu = s1v / cnt;
  float var = s2v / cnt - mu*mu;
  float rs = rsqrtf(var + 1e-5f);
  const float* g = is_e ? ge : gh;
  const float* b = is_e ? be : bh;
  float scale = rs * g[d];
  S[(is_e ? S_SCE : S_SCH) + d] = scale;
  S[(is_e ? S_SHE : S_SHH) + d] = b[d] - mu*scale;
}

// h = relu(BN(h)) in place
__global__ void h_norm_k(float* __restrict__ H, const float* __restrict__ S){
  size_t i = ((size_t)blockIdx.x*256 + threadIdx.x)*4;
  int col = (int)(i & 127);
  float4 v = *(const float4*)(H + i);
  const float* sc = S + S_SCH; const float* sh = S + S_SHH;
  v.x = fmaxf(v.x*sc[col+0] + sh[col+0], 0.f);
  v.y = fmaxf(v.y*sc[col+1] + sh[col+1], 0.f);
  v.z = fmaxf(v.z*sc[col+2] + sh[col+2], 0.f);
  v.w = fmaxf(v.w*sc[col+3] + sh[col+3], 0.f);
  *(float4*)(H + i) = v;
}

// final-layer e output norm (layers 1..3 norm on read inside edge_pre_k)
__global__ void e_norm_k(float* __restrict__ xe, const float* __restrict__ S){
  size_t i = ((size_t)blockIdx.x*256 + threadIdx.x)*4;
  int col = (int)(i & 127);
  float4 v = *(float4*)(xe + i);
  const float* sc = S + S_SCE; const float* sh = S + S_SHE;
  v.x = fmaxf(v.x*sc[col+0] + sh[col+0], 0.f);
  v.y = fmaxf(v.y*sc[col+1] + sh[col+1], 0.f);
  v.z = fmaxf(v.z*sc[col+2] + sh[col+2], 0.f);
  v.w = fmaxf(v.w*sc[col+3] + sh[col+3], 0.f);
  *(float4*)(xe + i) = v;
}

extern "C" void kernel_launch(void* const* d_in, const int* in_sizes, int n_in,
                              void* d_out, int out_size, void* d_ws, size_t ws_size,
                              hipStream_t stream){
  const float* h0  = (const float*)d_in[0];
  const float* e0  = (const float*)d_in[1];
  const int*  src  = (const int*)d_in[2];
  const int*  dst  = (const int*)d_in[3];
  const float* A   = (const float*)d_in[4];
  const float* B   = (const float*)d_in[5];
  const float* C   = (const float*)d_in[6];
  const float* V   = (const float*)d_in[7];
  const float* attn= (const float*)d_in[8];
  const float* gh  = (const float*)d_in[9];
  const float* bh  = (const float*)d_in[10];
  const float* ge  = (const float*)d_in[11];
  const float* be  = (const float*)d_in[12];

  // ws layout (~45.8 MB): WT | logits | XA XB XV (f16) | rowstart eidx cursor | S
  char* w = (char*)d_ws;
  unsigned short* WT = (unsigned short*)w;                 // 557,056
  float* logits  = (float*)(w + 557056);                   // E*4 = 3,200,000
  __half* XA     = (__half*)(w + 3757056);                 // N*128*2 = 12,800,000
  __half* XB     = (__half*)(w + 16557056);                // 12,800,000
  __half* XV     = (__half*)(w + 29357056);                // 12,800,000
  int* rowstart  = (int*)(w + 42157056);                   // (N+1)*4
  int* eidx      = (int*)(w + 42357120);                   // E*4 = 3,200,000
  int* cursor    = (int*)(w + 45557120);                   // N*4 = 200,000
  float* S       = (float*)(w + 45757120);                 // 2816 floats

  float* H    = (float*)d_out;                             // node state, in place
  float* ebuf = (float*)d_out + (size_t)NN*DD;             // e state (pre-norm xe), in place

  // one-time: weights, h0 copy, CSR-by-dst
  prep_weights_k<<<1024, 256, 0, stream>>>(A, B, C, V, WT);
  hipMemcpyAsync(H, h0, (size_t)NN*DD*4, hipMemcpyDeviceToDevice, stream);
  hipMemsetAsync(cursor, 0, NN*4, stream);
  hist_k<<<EE/256, 256, 0, stream>>>(dst, cursor);
  scan_k<<<1, 1024, 0, stream>>>(cursor, rowstart);
  hipMemsetAsync(cursor, 0, NN*4, stream);
  fill_k<<<EE/256, 256, 0, stream>>>(dst, rowstart, cursor, eidx);

  for (int l = 0; l < LL; l++){
    hipMemsetAsync(S, 0, S_ZERO_BYTES, stream);            // sums only; scale/shift persist
    const unsigned short* wtA = WT + (size_t)(l*4 + 0)*DD*136;
    const unsigned short* wtB = WT + (size_t)(l*4 + 1)*DD*136;
    const unsigned short* wtC = WT + (size_t)(l*4 + 2)*DD*136;
    const unsigned short* wtV = WT + (size_t)(l*4 + 3)*DD*136;

    node_proj_k<<<(NN + 63)/64, 256, 0, stream>>>(H, wtA, wtB, wtV, XA, XB, XV);
    if (l == 0)
      edge_pre_k<0><<<EE/64, 256, 0, stream>>>(e0, src, dst, XA, XB,
          wtC, attn + l*DD, ebuf, logits, S);
    else
      edge_pre_k<1><<<EE/64, 256, 0, stream>>>(ebuf, src, dst, XA, XB,
          wtC, attn + l*DD, ebuf, logits, S);
    node_agg_k<<<(NN + 3)/4, 256, 0, stream>>>(rowstart, eidx, src, logits, XV, H);
    h_stats_k<<<(NN + 63)/64, 256, 0, stream>>>(H, S, S + 128);
    finalize_k<<<1, 256, 0, stream>>>(S, gh + l*DD, bh + l*DD, ge + l*DD, be + l*DD);
    h_norm_k<<<(NN*DD)/1024, 256, 0, stream>>>(H, S);
  }
  e_norm_k<<<(EE*DD)/1024, 256, 0, stream>>>(ebuf, S);     // final e output norm
}